// Round 1
// baseline (257.610 us; speedup 1.0000x reference)
//
#include <hip/hip_runtime.h>

#define SEQ 2048
#define HID 128

// ---------------------------------------------------------------------------
// Encoder: h2 = relu(x @ w1 + b1) @ w2 + b2        x:[B*S,6] -> out:[B*S,128]
// 64 rows per block, 256 threads (16x16), each thread 4 rows x 8 cols.
// ---------------------------------------------------------------------------
__global__ __launch_bounds__(256) void enc_kernel(
    const float* __restrict__ x,
    const float* __restrict__ w1, const float* __restrict__ b1,
    const float* __restrict__ w2, const float* __restrict__ b2,
    float* __restrict__ out)
{
  __shared__ float xs[64][8];
  __shared__ float w1s[6][128];
  __shared__ float b1s[128];
  __shared__ float b2s[128];
  __shared__ float h1s[64][133];                 // stride 133: conflict-free k-broadcast reads
  __shared__ __align__(16) float w2s[32 * 128];  // one 32-wide K slice of w2

  const int tid = threadIdx.x;
  const int tx = tid & 15, ty = tid >> 4;
  const long long row0 = (long long)blockIdx.x * 64;

  for (int f = tid; f < 64 * 6; f += 256) xs[f / 6][f % 6] = x[row0 * 6 + f];
  for (int f = tid; f < 6 * 128; f += 256) w1s[f >> 7][f & 127] = w1[f];
  if (tid < 128) { b1s[tid] = b1[tid]; b2s[tid] = b2[tid]; }
  __syncthreads();

  // h1 = relu(x @ w1 + b1), K = 6
  #pragma unroll
  for (int i = 0; i < 4; ++i) {
    const int m = ty * 4 + i;
    #pragma unroll
    for (int j = 0; j < 8; ++j) {
      const int n = tx * 8 + j;
      float v = b1s[n];
      #pragma unroll
      for (int k = 0; k < 6; ++k) v = fmaf(xs[m][k], w1s[k][n], v);
      h1s[m][n] = v > 0.f ? v : 0.f;
    }
  }

  float acc[4][8];
  #pragma unroll
  for (int i = 0; i < 4; ++i)
    #pragma unroll
    for (int j = 0; j < 8; ++j) acc[i][j] = 0.f;

  for (int kb = 0; kb < 4; ++kb) {
    __syncthreads();  // h1s writes done (kb==0) / prior slice reads done
    for (int f = tid; f < 1024; f += 256)
      ((float4*)w2s)[f] = ((const float4*)(w2 + kb * 32 * HID))[f];
    __syncthreads();
    #pragma unroll 4
    for (int k = 0; k < 32; ++k) {
      const int kk = kb * 32 + k;
      float av[4];
      #pragma unroll
      for (int i = 0; i < 4; ++i) av[i] = h1s[ty * 4 + i][kk];  // broadcast read
      const float4 wv0 = *(const float4*)&w2s[k * HID + tx * 8];
      const float4 wv1 = *(const float4*)&w2s[k * HID + tx * 8 + 4];
      const float wv[8] = {wv0.x, wv0.y, wv0.z, wv0.w, wv1.x, wv1.y, wv1.z, wv1.w};
      #pragma unroll
      for (int i = 0; i < 4; ++i)
        #pragma unroll
        for (int j = 0; j < 8; ++j) acc[i][j] = fmaf(av[i], wv[j], acc[i][j]);
    }
  }

  // epilogue: + b2 (no relu), coalesced float4 stores
  #pragma unroll
  for (int i = 0; i < 4; ++i) {
    const long long r = row0 + ty * 4 + i;
    #pragma unroll
    for (int j = 0; j < 8; j += 4) {
      float4 o;
      o.x = acc[i][j + 0] + b2s[tx * 8 + j + 0];
      o.y = acc[i][j + 1] + b2s[tx * 8 + j + 1];
      o.z = acc[i][j + 2] + b2s[tx * 8 + j + 2];
      o.w = acc[i][j + 3] + b2s[tx * 8 + j + 3];
      *(float4*)&out[r * HID + tx * 8 + j] = o;
    }
  }
}

// ---------------------------------------------------------------------------
// Graph conv layer: out = relu(band_agg(h @ W + b))
// Block = (seq tile of 128, batch). Computes t for 130 rows (1 halo each side:
// main 8x8 register tile covers LDS rows 0..127 (s0-1..s0+126), rows 128/129
// computed as 1 extra output per thread). Aggregation via LDS exchange in two
// 64-column halves, reusing (union-aliased) the GEMM staging LDS.
// DO_POOL: skip the global store, accumulate column sums into pooled[b][128].
// ---------------------------------------------------------------------------
template <bool DO_POOL>
__global__ __launch_bounds__(256) void gc_kernel(
    const float* __restrict__ hin, const float* __restrict__ W,
    const float* __restrict__ bias, float* __restrict__ hout,
    float* __restrict__ pooled)
{
  // union: [ As[130][36] | Ws[32][128] ]  vs  [ tbuf[130][68] ]
  __shared__ __align__(16) float smem[130 * 68];   // 35360 B
  float (*As)[36]  = (float(*)[36])smem;           // A k-slice, row-major
  float (*Ws)[128] = (float(*)[128])(smem + 130 * 36);
  float (*tbuf)[68] = (float(*)[68])smem;
  __shared__ float bsh[128];
  __shared__ float psum[4][64];

  const int tid = threadIdx.x;
  const int tx = tid & 15, ty = tid >> 4;
  const int s0 = blockIdx.x * 128;
  const int b = blockIdx.y;
  const float* hb = hin + (long long)b * SEQ * HID;

  if (tid < 128) bsh[tid] = bias[tid];

  float acc[8][8];
  #pragma unroll
  for (int i = 0; i < 8; ++i)
    #pragma unroll
    for (int j = 0; j < 8; ++j) acc[i][j] = 0.f;
  float hacc = 0.f;
  const int hm = (tid < 128) ? 128 : 129;  // halo LDS row (wave-uniform)
  const int hcol = tid & 127;

  for (int kb = 0; kb < 4; ++kb) {
    __syncthreads();
    // stage A slice: 130 rows x 32 k, zero-fill outside the sequence
    for (int f = tid; f < 130 * 8; f += 256) {
      const int m = f >> 3, kq = f & 7;
      const int s = s0 - 1 + m;
      float4 v = make_float4(0.f, 0.f, 0.f, 0.f);
      if (s >= 0 && s < SEQ) v = *(const float4*)&hb[(long long)s * HID + kb * 32 + kq * 4];
      *(float4*)&As[m][kq * 4] = v;
    }
    // stage W slice: 32 x 128
    for (int f = tid; f < 1024; f += 256)
      ((float4*)Ws)[f] = ((const float4*)(W + kb * 32 * HID))[f];
    __syncthreads();
    #pragma unroll 4
    for (int k = 0; k < 32; ++k) {
      float av[8];
      #pragma unroll
      for (int i = 0; i < 8; ++i) av[i] = As[ty * 8 + i][k];  // full broadcast
      const float4 wv0 = *(const float4*)&Ws[k][tx * 8];
      const float4 wv1 = *(const float4*)&Ws[k][tx * 8 + 4];
      const float wv[8] = {wv0.x, wv0.y, wv0.z, wv0.w, wv1.x, wv1.y, wv1.z, wv1.w};
      #pragma unroll
      for (int i = 0; i < 8; ++i)
        #pragma unroll
        for (int j = 0; j < 8; ++j) acc[i][j] = fmaf(av[i], wv[j], acc[i][j]);
      hacc = fmaf(As[hm][k], Ws[k][hcol], hacc);  // halo row output
    }
  }

  float* houtb = DO_POOL ? nullptr : hout + (long long)b * SEQ * HID;

  for (int half = 0; half < 2; ++half) {
    __syncthreads();  // GEMM LDS reads / previous half's agg reads done
    // write t (= acc + bias; 0 outside sequence) for this column half
    if ((tx >> 3) == half) {
      const int nb = (tx & 7) * 8;
      #pragma unroll
      for (int i = 0; i < 8; ++i) {
        const int r = ty * 8 + i;
        const bool valid = (s0 - 1 + r) >= 0;  // only r==0 at s0==0 is invalid
        #pragma unroll
        for (int j = 0; j < 8; ++j)
          tbuf[r][nb + j] = valid ? acc[i][j] + bsh[half * 64 + nb + j] : 0.f;
      }
    }
    if ((hcol >> 6) == half) {
      const int s = s0 - 1 + hm;                // s0+127 (always valid) or s0+128
      tbuf[hm][hcol & 63] = (s < SEQ) ? hacc + bsh[hcol] : 0.f;
    }
    __syncthreads();
    // aggregate + relu (+ store or pool)
    float pacc = 0.f;
    const int n = tid & 63;
    const int rb = tid >> 6;
    for (int p = 0; p < 32; ++p) {
      const int ro = p * 4 + rb;   // output row within tile, 0..127
      const float sum = tbuf[ro][n] + tbuf[ro + 1][n] + tbuf[ro + 2][n];
      const int s = s0 + ro;
      const float invd = (s == 0 || s == SEQ - 1) ? (1.0f / (2.0f + 1e-8f))
                                                  : (1.0f / (3.0f + 1e-8f));
      float o = sum * invd;
      o = o > 0.f ? o : 0.f;
      if (DO_POOL) pacc += o;
      else houtb[(long long)s * HID + half * 64 + n] = o;
    }
    if (DO_POOL) {
      psum[rb][n] = pacc;
      __syncthreads();
      if (tid < 64) {
        const float v = psum[0][tid] + psum[1][tid] + psum[2][tid] + psum[3][tid];
        atomicAdd(&pooled[b * HID + half * 64 + tid], v);
      }
    }
  }
}

// ---------------------------------------------------------------------------
// Classifier: out = relu(mean @ w1 + b1) @ w2 + b2, one block per batch row
// ---------------------------------------------------------------------------
__global__ __launch_bounds__(64) void cls_kernel(
    const float* __restrict__ pooled,
    const float* __restrict__ w1, const float* __restrict__ b1,
    const float* __restrict__ w2, const float* __restrict__ b2,
    float* __restrict__ out)
{
  __shared__ float ms[128];
  __shared__ float hid[64];
  const int b = blockIdx.x, tid = threadIdx.x;
  ms[tid] = pooled[b * 128 + tid] * (1.0f / 2048.0f);
  ms[tid + 64] = pooled[b * 128 + 64 + tid] * (1.0f / 2048.0f);
  __syncthreads();
  float a = b1[tid];
  for (int k = 0; k < 128; ++k) a = fmaf(ms[k], w1[k * 64 + tid], a);
  hid[tid] = a > 0.f ? a : 0.f;
  __syncthreads();
  if (tid < 3) {
    float o = b2[tid];
    for (int k = 0; k < 64; ++k) o = fmaf(hid[k], w2[k * 3 + tid], o);
    out[b * 3 + tid] = o;
  }
}

extern "C" void kernel_launch(void* const* d_in, const int* in_sizes, int n_in,
                              void* d_out, int out_size, void* d_ws, size_t ws_size,
                              hipStream_t stream) {
  (void)in_sizes; (void)n_in; (void)out_size; (void)ws_size;
  const float* x      = (const float*)d_in[0];
  const float* enc_w1 = (const float*)d_in[1];
  const float* enc_b1 = (const float*)d_in[2];
  const float* enc_w2 = (const float*)d_in[3];
  const float* enc_b2 = (const float*)d_in[4];
  const float* gc1_w  = (const float*)d_in[5];
  const float* gc1_b  = (const float*)d_in[6];
  const float* gc2_w  = (const float*)d_in[7];
  const float* gc2_b  = (const float*)d_in[8];
  const float* gc3_w  = (const float*)d_in[9];
  const float* gc3_b  = (const float*)d_in[10];
  const float* cls_w1 = (const float*)d_in[11];
  const float* cls_b1 = (const float*)d_in[12];
  const float* cls_w2 = (const float*)d_in[13];
  const float* cls_b2 = (const float*)d_in[14];

  const size_t n_elems = (size_t)32 * SEQ * HID;  // 8.39M floats = 33.55 MB
  float* buf0   = (float*)d_ws;
  float* buf1   = buf0 + n_elems;
  float* pooled = buf1 + n_elems;

  hipMemsetAsync(pooled, 0, 32 * HID * sizeof(float), stream);

  enc_kernel<<<dim3(32 * SEQ / 64), 256, 0, stream>>>(x, enc_w1, enc_b1, enc_w2, enc_b2, buf0);
  dim3 g(SEQ / 128, 32);
  gc_kernel<false><<<g, 256, 0, stream>>>(buf0, gc1_w, gc1_b, buf1, nullptr);
  gc_kernel<false><<<g, 256, 0, stream>>>(buf1, gc2_w, gc2_b, buf0, nullptr);
  gc_kernel<true ><<<g, 256, 0, stream>>>(buf0, gc3_w, gc3_b, nullptr, pooled);
  cls_kernel<<<dim3(32), 64, 0, stream>>>(pooled, cls_w1, cls_b1, cls_w2, cls_b2, (float*)d_out);
}